// Round 4
// baseline (225.953 us; speedup 1.0000x reference)
//
#include <hip/hip_runtime.h>
#include <stdint.h>

typedef __attribute__((ext_vector_type(8))) short  bf16x8;
typedef __attribute__((ext_vector_type(4))) float  f32x4;
typedef __attribute__((ext_vector_type(4))) int    int4v;
typedef __attribute__((ext_vector_type(4))) float  float4v;
typedef __attribute__((ext_vector_type(4))) unsigned int uint4v;
typedef __attribute__((ext_vector_type(2))) unsigned int uint2v;

#define NN   8192   // nodes
#define DIN  512
#define DOUT 256

#define BM     64
#define BK     64
#define KSPLIT 4
#define KS     (NN / KSPLIT)   // 2048 per split
#define NT     (KS / BK)       // 32 tiles

#define MFMA16(a, b, c) __builtin_amdgcn_mfma_f32_16x16x32_bf16((a), (b), (c), 0, 0, 0)

__device__ __forceinline__ unsigned short f2bf(float f) {
  unsigned u = __float_as_uint(f);
  return (unsigned short)((u + 0x7FFFu + ((u >> 16) & 1u)) >> 16);
}

// ---------------------------------------------------------------------------
// Kernel 0: Wt[n][c] = bf16(W[c][n]).  W: [512][256] f32 -> Wt: [256][512] bf16
// ---------------------------------------------------------------------------
__global__ void k_wt(const float* __restrict__ W, unsigned short* __restrict__ Wt) {
  int n = blockIdx.x; // 0..255
  for (int c = threadIdx.x; c < DIN; c += blockDim.x)
    Wt[n * DIN + c] = f2bf(W[c * DOUT + n]);
}

// ---------------------------------------------------------------------------
// Kernel 1: xw_t[n][m] = sum_c x[m][c] * W[c][n]   (bf16 out, transposed)
// ---------------------------------------------------------------------------
__global__ __launch_bounds__(256) void k_xwt(const float* __restrict__ x,
                                             const unsigned short* __restrict__ Wt,
                                             unsigned short* __restrict__ xw_t) {
  const int mb = blockIdx.x >> 1, nb = blockIdx.x & 1;
  const int tid = threadIdx.x;
  const int w = tid >> 6, l = tid & 63;
  const int wm = w >> 1, wn = w & 1;
  const int lr = l & 15, lg = l >> 4;
  const int m_base = mb * 128 + wm * 64;
  const int n_base = nb * 128 + wn * 64;

  f32x4 acc[4][4];
  for (int i = 0; i < 4; ++i)
    for (int j = 0; j < 4; ++j) acc[i][j] = (f32x4)0.0f;

  for (int c0 = 0; c0 < DIN; c0 += 32) {
    const int c = c0 + lg * 8;
    bf16x8 af[4], bfv[4];
#pragma unroll
    for (int mt = 0; mt < 4; ++mt) {
      const float* xp = x + (size_t)(m_base + mt * 16 + lr) * DIN + c;
      float4v x0 = *reinterpret_cast<const float4v*>(xp);
      float4v x1 = *reinterpret_cast<const float4v*>(xp + 4);
      bf16x8 a;
#pragma unroll
      for (int j = 0; j < 4; ++j) {
        a[j]     = (short)f2bf(x0[j]);
        a[4 + j] = (short)f2bf(x1[j]);
      }
      af[mt] = a;
    }
#pragma unroll
    for (int nt = 0; nt < 4; ++nt)
      bfv[nt] = *reinterpret_cast<const bf16x8*>(Wt + (size_t)(n_base + nt * 16 + lr) * DIN + c);
#pragma unroll
    for (int mt = 0; mt < 4; ++mt)
#pragma unroll
      for (int nt = 0; nt < 4; ++nt)
        acc[mt][nt] = MFMA16(af[mt], bfv[nt], acc[mt][nt]);
  }

#pragma unroll
  for (int nt = 0; nt < 4; ++nt) {
    const int n = n_base + nt * 16 + lr;
#pragma unroll
    for (int mt = 0; mt < 4; ++mt) {
      const int m = m_base + mt * 16 + lg * 4;
      unsigned short b0 = f2bf(acc[mt][nt][0]), b1 = f2bf(acc[mt][nt][1]);
      unsigned short b2 = f2bf(acc[mt][nt][2]), b3 = f2bf(acc[mt][nt][3]);
      uint2v p;
      p[0] = (unsigned)b0 | ((unsigned)b1 << 16);
      p[1] = (unsigned)b2 | ((unsigned)b3 << 16);
      *reinterpret_cast<uint2v*>(xw_t + (size_t)n * NN + m) = p;
    }
  }
}

// ---------------------------------------------------------------------------
// Kernel 2: barrier-free split-K partial of  outp[ks] = A[rows,kslice]*xw[kslice,:]
// BM=64, BN=256, BK=64, KSPLIT=4. grid 512 (2 blocks/CU), block 256 = 4 waves,
// wave = 32m x 128n (wm=w>>1, wn=w&1). NO LDS, NO barriers: each wave builds
// its A-fragments directly from global adj (int32 0/1 -> bf16 via
// (a|b<<16)*0x3F80), prefetched one K-tile ahead; B single-buffered from the
// XCD-pinned L2-resident xw_t slice. deg partials fused (wn==0 waves).
// ---------------------------------------------------------------------------
#define PACKW(a, b) ((unsigned)((a) | ((b) << 16)) * 0x3F80u)

__global__ __launch_bounds__(256) void k_agg(const int* __restrict__ adj,
                                             const unsigned short* __restrict__ xw_t,
                                             float* __restrict__ outp,
                                             int* __restrict__ degp) {
  const int tid = threadIdx.x;
  const int w = tid >> 6, l = tid & 63;
  const int lr = l & 15, lg = l >> 4;
  const int wm = w >> 1, wn = w & 1;

  const int bid = blockIdx.x;
  const int ks = (bid & 7) >> 1;                   // K-split 0..3, 2 XCDs each
  const int rb = ((bid >> 3) << 1) | (bid & 1);    // row-block 0..127
  const int row0 = rb * BM;
  const int kbase = ks * KS;

  // A: rows row0 + wm*32 + {0,16} + lr, k = kbase + t*64 + kf*32 + lg*8
  const int* aP0 = adj + (size_t)(row0 + wm * 32 + lr) * NN + kbase + lg * 8;
  const int* aP1 = aP0 + (size_t)16 * NN;
  // B: n = wn*128 + nf*16 + lr, k same
  const unsigned short* bP = xw_t + (size_t)(wn * 128 + lr) * NN + kbase + lg * 8;

  f32x4 acc[2][8];
#pragma unroll
  for (int i = 0; i < 2; ++i)
#pragma unroll
    for (int j = 0; j < 8; ++j) acc[i][j] = (f32x4)0.0f;

  int4v ar[8];        // raw next-tile A: [mf*4 + kf*2 + half]
  bf16x8 af[2][2];    // current converted A [mf][kf]
  bf16x8 bb[16];      // current B [nf*2+kf]
  int cnt0 = 0, cnt1 = 0;

#define LOADA(t) do {                                                          \
    ar[0] = *reinterpret_cast<const int4v*>(aP0 + (size_t)(t) * BK);           \
    ar[1] = *reinterpret_cast<const int4v*>(aP0 + (size_t)(t) * BK + 4);       \
    ar[2] = *reinterpret_cast<const int4v*>(aP0 + (size_t)(t) * BK + 32);      \
    ar[3] = *reinterpret_cast<const int4v*>(aP0 + (size_t)(t) * BK + 36);      \
    ar[4] = *reinterpret_cast<const int4v*>(aP1 + (size_t)(t) * BK);           \
    ar[5] = *reinterpret_cast<const int4v*>(aP1 + (size_t)(t) * BK + 4);       \
    ar[6] = *reinterpret_cast<const int4v*>(aP1 + (size_t)(t) * BK + 32);      \
    ar[7] = *reinterpret_cast<const int4v*>(aP1 + (size_t)(t) * BK + 36);      \
  } while (0)

#define CONV do {                                                              \
    _Pragma("unroll")                                                          \
    for (int mf_ = 0; mf_ < 2; ++mf_) {                                        \
      _Pragma("unroll")                                                        \
      for (int kf_ = 0; kf_ < 2; ++kf_) {                                      \
        const int4v va = ar[mf_ * 4 + kf_ * 2];                                \
        const int4v vb = ar[mf_ * 4 + kf_ * 2 + 1];                            \
        uint4v q_;                                                             \
        q_[0] = PACKW(va[0], va[1]); q_[1] = PACKW(va[2], va[3]);              \
        q_[2] = PACKW(vb[0], vb[1]); q_[3] = PACKW(vb[2], vb[3]);              \
        af[mf_][kf_] = *reinterpret_cast<bf16x8*>(&q_);                        \
        if (wn == 0) {                                                         \
          int s_ = va[0] + va[1] + va[2] + va[3] + vb[0] + vb[1] + vb[2] + vb[3]; \
          if (mf_ == 0) cnt0 += s_; else cnt1 += s_;                           \
        }                                                                      \
      }                                                                        \
    }                                                                          \
  } while (0)

#define LOADB(t) do {                                                          \
    _Pragma("unroll")                                                          \
    for (int nf_ = 0; nf_ < 8; ++nf_) {                                        \
      bb[nf_ * 2 + 0] = *reinterpret_cast<const bf16x8*>(bP + (size_t)nf_ * 16 * NN + (size_t)(t) * BK);      \
      bb[nf_ * 2 + 1] = *reinterpret_cast<const bf16x8*>(bP + (size_t)nf_ * 16 * NN + (size_t)(t) * BK + 32); \
    }                                                                          \
  } while (0)

#define COMPUTE do {                                                           \
    _Pragma("unroll")                                                          \
    for (int kf_ = 0; kf_ < 2; ++kf_) {                                        \
      _Pragma("unroll")                                                        \
      for (int mf_ = 0; mf_ < 2; ++mf_) {                                      \
        _Pragma("unroll")                                                      \
        for (int nf_ = 0; nf_ < 8; ++nf_)                                      \
          acc[mf_][nf_] = MFMA16(af[mf_][kf_], bb[nf_ * 2 + kf_], acc[mf_][nf_]); \
      }                                                                        \
    }                                                                          \
  } while (0)

  LOADA(0);
  CONV; // waits for tile 0 A

  for (int t = 0; t < NT; ++t) {
    if (t + 1 < NT) LOADA(t + 1);  // HBM, lands during this tile's compute
    LOADB(t);                      // L2-resident slice
    COMPUTE;                       // af ready; bb waits briefly
    if (t + 1 < NT) CONV;          // convert next tile's A, prep af
  }
#undef LOADA
#undef CONV
#undef LOADB
#undef COMPUTE

  // deg partials: rows counted once by wn==0 waves; reduce over lg groups
  if (wn == 0) {
    cnt0 += __shfl_xor(cnt0, 16); cnt0 += __shfl_xor(cnt0, 32);
    cnt1 += __shfl_xor(cnt1, 16); cnt1 += __shfl_xor(cnt1, 32);
    if (lg == 0) {
      degp[ks * NN + row0 + wm * 32 + lr]      = cnt0;
      degp[ks * NN + row0 + wm * 32 + 16 + lr] = cnt1;
    }
  }

  // partial C store (exclusive ownership: no atomics, no init needed)
  float* po = outp + (size_t)ks * NN * DOUT;
#pragma unroll
  for (int mf = 0; mf < 2; ++mf)
#pragma unroll
    for (int nf = 0; nf < 8; ++nf)
#pragma unroll
      for (int r = 0; r < 4; ++r) {
        const int row = row0 + wm * 32 + mf * 16 + lg * 4 + r;
        const int col = wn * 128 + nf * 16 + lr;
        po[(size_t)row * DOUT + col] = acc[mf][nf][r];
      }
}

// ---------------------------------------------------------------------------
// Kernel 3: out = (sum_ks outp[ks]) / (sum_ks degp[ks])
// ---------------------------------------------------------------------------
__global__ __launch_bounds__(256) void k_div(const float* __restrict__ outp,
                                             const int* __restrict__ degp,
                                             float* __restrict__ out) {
  const int idx = blockIdx.x * 256 + threadIdx.x;
  const size_t i4 = (size_t)idx * 4;
  const int row = (int)(i4 >> 8); // DOUT=256
  float4v v = *reinterpret_cast<const float4v*>(outp + i4);
  float4v v1 = *reinterpret_cast<const float4v*>(outp + (size_t)1 * NN * DOUT + i4);
  float4v v2 = *reinterpret_cast<const float4v*>(outp + (size_t)2 * NN * DOUT + i4);
  float4v v3 = *reinterpret_cast<const float4v*>(outp + (size_t)3 * NN * DOUT + i4);
  const int d = degp[row] + degp[NN + row] + degp[2 * NN + row] + degp[3 * NN + row];
  const float s = 1.0f / (float)d;
  v[0] = (v[0] + v1[0] + v2[0] + v3[0]) * s;
  v[1] = (v[1] + v1[1] + v2[1] + v3[1]) * s;
  v[2] = (v[2] + v1[2] + v2[2] + v3[2]) * s;
  v[3] = (v[3] + v1[3] + v2[3] + v3[3]) * s;
  *reinterpret_cast<float4v*>(out + i4) = v;
}

// ---------------------------------------------------------------------------
extern "C" void kernel_launch(void* const* d_in, const int* in_sizes, int n_in,
                              void* d_out, int out_size, void* d_ws, size_t ws_size,
                              hipStream_t stream) {
  const float* x   = (const float*)d_in[0]; // [8192][512] f32
  const int*   adj = (const int*)d_in[1];   // [8192][8192] i32 (0/1)
  const float* W   = (const float*)d_in[2]; // [512][256] f32
  float* out = (float*)d_out;               // [8192][256] f32

  char* ws = (char*)d_ws;
  unsigned short* xw_t = (unsigned short*)ws;                              // 4 MB
  unsigned short* Wt   = (unsigned short*)(ws + (size_t)4 * 1024 * 1024);  // 256 KB
  int*            degp = (int*)(ws + (size_t)4 * 1024 * 1024 + 512 * 1024);// 128 KB (4 x 8192)
  float*          outp = (float*)(ws + (size_t)5 * 1024 * 1024);           // 32 MB (4 x 8 MB)

  k_wt<<<256, 128, 0, stream>>>(W, Wt);
  k_xwt<<<128, 256, 0, stream>>>(x, Wt, xw_t);
  k_agg<<<(NN / BM) * KSPLIT, 256, 0, stream>>>(adj, xw_t, outp, degp);
  k_div<<<(NN * DOUT) / (256 * 4), 256, 0, stream>>>(outp, degp, out);
}

// Round 5
// 215.710 us; speedup vs baseline: 1.0475x; 1.0475x over previous
//
#include <hip/hip_runtime.h>
#include <stdint.h>

typedef __attribute__((ext_vector_type(8))) short  bf16x8;
typedef __attribute__((ext_vector_type(4))) float  f32x4;
typedef __attribute__((ext_vector_type(4))) int    int4v;
typedef __attribute__((ext_vector_type(4))) float  float4v;
typedef __attribute__((ext_vector_type(4))) unsigned int uint4v;
typedef __attribute__((ext_vector_type(2))) unsigned int uint2v;

#define NN   8192   // nodes
#define DIN  512
#define DOUT 256

#define BM     64
#define BK     64
#define KSPLIT 4
#define KS     (NN / KSPLIT)   // 2048 per split
#define NT     (KS / BK)       // 32 tiles
#define NW     (NN / 32)       // 256 dwords of bits per row
#define LDW    68              // padded LDS dword stride (16B-aligned, ~2-way banks)

#define MFMA16(a, b, c) __builtin_amdgcn_mfma_f32_16x16x32_bf16((a), (b), (c), 0, 0, 0)

__device__ __forceinline__ unsigned short f2bf(float f) {
  unsigned u = __float_as_uint(f);
  return (unsigned short)((u + 0x7FFFu + ((u >> 16) & 1u)) >> 16);
}

// ---------------------------------------------------------------------------
// Kernel 0: Wt[n][c] = bf16(W[c][n]).  W: [512][256] f32 -> Wt: [256][512] bf16
// ---------------------------------------------------------------------------
__global__ void k_wt(const float* __restrict__ W, unsigned short* __restrict__ Wt) {
  int n = blockIdx.x; // 0..255
  for (int c = threadIdx.x; c < DIN; c += blockDim.x)
    Wt[n * DIN + c] = f2bf(W[c * DOUT + n]);
}

// ---------------------------------------------------------------------------
// Kernel 1: xw_t[n][m] = sum_c x[m][c] * W[c][n]   (bf16 out, transposed)
// ---------------------------------------------------------------------------
__global__ __launch_bounds__(256) void k_xwt(const float* __restrict__ x,
                                             const unsigned short* __restrict__ Wt,
                                             unsigned short* __restrict__ xw_t) {
  const int mb = blockIdx.x >> 1, nb = blockIdx.x & 1;
  const int tid = threadIdx.x;
  const int w = tid >> 6, l = tid & 63;
  const int wm = w >> 1, wn = w & 1;
  const int lr = l & 15, lg = l >> 4;
  const int m_base = mb * 128 + wm * 64;
  const int n_base = nb * 128 + wn * 64;

  f32x4 acc[4][4];
  for (int i = 0; i < 4; ++i)
    for (int j = 0; j < 4; ++j) acc[i][j] = (f32x4)0.0f;

  for (int c0 = 0; c0 < DIN; c0 += 32) {
    const int c = c0 + lg * 8;
    bf16x8 af[4], bfv[4];
#pragma unroll
    for (int mt = 0; mt < 4; ++mt) {
      const float* xp = x + (size_t)(m_base + mt * 16 + lr) * DIN + c;
      float4v x0 = *reinterpret_cast<const float4v*>(xp);
      float4v x1 = *reinterpret_cast<const float4v*>(xp + 4);
      bf16x8 a;
#pragma unroll
      for (int j = 0; j < 4; ++j) {
        a[j]     = (short)f2bf(x0[j]);
        a[4 + j] = (short)f2bf(x1[j]);
      }
      af[mt] = a;
    }
#pragma unroll
    for (int nt = 0; nt < 4; ++nt)
      bfv[nt] = *reinterpret_cast<const bf16x8*>(Wt + (size_t)(n_base + nt * 16 + lr) * DIN + c);
#pragma unroll
    for (int mt = 0; mt < 4; ++mt)
#pragma unroll
      for (int nt = 0; nt < 4; ++nt)
        acc[mt][nt] = MFMA16(af[mt], bfv[nt], acc[mt][nt]);
  }

#pragma unroll
  for (int nt = 0; nt < 4; ++nt) {
    const int n = n_base + nt * 16 + lr;
#pragma unroll
    for (int mt = 0; mt < 4; ++mt) {
      const int m = m_base + mt * 16 + lg * 4;
      unsigned short b0 = f2bf(acc[mt][nt][0]), b1 = f2bf(acc[mt][nt][1]);
      unsigned short b2 = f2bf(acc[mt][nt][2]), b3 = f2bf(acc[mt][nt][3]);
      uint2v p;
      p[0] = (unsigned)b0 | ((unsigned)b1 << 16);
      p[1] = (unsigned)b2 | ((unsigned)b3 << 16);
      *reinterpret_cast<uint2v*>(xw_t + (size_t)n * NN + m) = p;
    }
  }
}

// ---------------------------------------------------------------------------
// Kernel 2: pack adj int32 -> 1-bit mask + row degrees. Pure streaming.
// grid 2048, block 256; each block packs 4 full rows (8192 ints -> 256 dwords).
// thread t, chunk c: reads int4v at row*NN + c*1024 + t*4 (coalesced),
// nibble -> dword via 8-lane shfl-OR; deg via full reduce.
// ---------------------------------------------------------------------------
__global__ __launch_bounds__(256) void k_pack(const int* __restrict__ adj,
                                              unsigned int* __restrict__ bits,
                                              int* __restrict__ deg) {
  __shared__ int wsum[4];
  const int tid = threadIdx.x;
  const int w = tid >> 6;

  for (int rr = 0; rr < 4; ++rr) {
    const int row = blockIdx.x * 4 + rr;
    const int* src = adj + (size_t)row * NN;
    int cnt = 0;
#pragma unroll
    for (int c = 0; c < 8; ++c) {
      int4v v = *reinterpret_cast<const int4v*>(src + c * 1024 + tid * 4);
      cnt += v[0] + v[1] + v[2] + v[3];
      unsigned nib = (unsigned)(v[0] | (v[1] << 1) | (v[2] << 2) | (v[3] << 3));
      unsigned word = nib << ((tid & 7) * 4);
      word |= __shfl_xor(word, 1);
      word |= __shfl_xor(word, 2);
      word |= __shfl_xor(word, 4);
      if ((tid & 7) == 0)
        bits[(size_t)row * NW + c * 32 + (tid >> 3)] = word;
    }
    cnt += __shfl_xor(cnt, 1);
    cnt += __shfl_xor(cnt, 2);
    cnt += __shfl_xor(cnt, 4);
    cnt += __shfl_xor(cnt, 8);
    cnt += __shfl_xor(cnt, 16);
    cnt += __shfl_xor(cnt, 32);
    if ((tid & 63) == 0) wsum[w] = cnt;
    __syncthreads();
    if (tid == 0) deg[row] = wsum[0] + wsum[1] + wsum[2] + wsum[3];
    __syncthreads();
  }
}

// ---------------------------------------------------------------------------
// Kernel 3: split-K partial  outp[ks] = A_bits[rows,kslice] * xw[kslice,:]
// BM=64, BN=256, BK=64, KSPLIT=4. grid 512 (2 blocks/CU), block 256 = 4 waves,
// wave = 32m x 128n. A-bits (16 KB) staged once to LDS, then ZERO barriers:
// inner loop = 16 B-loads (L2-resident, XCD-pinned slice) + 1-2 ds_read_b64
// + in-register bit->bf16 expansion + 32 MFMA. Exclusive partial stores.
// ---------------------------------------------------------------------------
__global__ __launch_bounds__(256) void k_agg(const unsigned int* __restrict__ bits,
                                             const unsigned short* __restrict__ xw_t,
                                             float* __restrict__ outp) {
  __shared__ unsigned int ab[BM * LDW];

  const int tid = threadIdx.x;
  const int w = tid >> 6, l = tid & 63;
  const int lr = l & 15, lg = l >> 4;
  const int wm = w >> 1, wn = w & 1;

  const int bid = blockIdx.x;
  const int ks = (bid & 7) >> 1;                     // K-split, XCD-pinned (2 XCDs/split)
  const int rb = ((bid >> 3) << 1) | (bid & 1);      // row-block 0..127
  const int row0 = rb * BM;
  const int kbase = ks * KS;

  // stage A-bits: 64 rows x 64 dwords -> LDS (once)
  {
    const int r = tid >> 2, c0 = (tid & 3) * 16;
    const unsigned int* g = bits + (size_t)(row0 + r) * NW + (kbase >> 5) + c0;
#pragma unroll
    for (int i = 0; i < 4; ++i)
      *reinterpret_cast<uint4v*>(&ab[r * LDW + c0 + i * 4]) =
          *reinterpret_cast<const uint4v*>(g + i * 4);
  }
  __syncthreads();

  const unsigned short* bP = xw_t + (size_t)(wn * 128 + lr) * NN + kbase + lg * 8;
  const unsigned int* a0 = &ab[(wm * 32 + lr) * LDW];
  const unsigned int* a1 = &ab[(wm * 32 + 16 + lr) * LDW];

  f32x4 acc[2][8];
#pragma unroll
  for (int i = 0; i < 2; ++i)
#pragma unroll
    for (int j = 0; j < 8; ++j) acc[i][j] = (f32x4)0.0f;

  for (int t = 0; t < NT; ++t) {
    bf16x8 bb[16];
#pragma unroll
    for (int nf = 0; nf < 8; ++nf) {
      bb[nf * 2 + 0] = *reinterpret_cast<const bf16x8*>(bP + (size_t)nf * 16 * NN + t * BK);
      bb[nf * 2 + 1] = *reinterpret_cast<const bf16x8*>(bP + (size_t)nf * 16 * NN + t * BK + 32);
    }
    uint2v A0 = *reinterpret_cast<const uint2v*>(a0 + 2 * t); // kf=0,1 dwords, row lr
    uint2v A1 = *reinterpret_cast<const uint2v*>(a1 + 2 * t); // row lr+16
#pragma unroll
    for (int kf = 0; kf < 2; ++kf) {
#pragma unroll
      for (int mf = 0; mf < 2; ++mf) {
        const unsigned a32 = mf ? A1[kf] : A0[kf];
        uint4v q;
#pragma unroll
        for (int j = 0; j < 4; ++j) {
          unsigned b2 = (a32 >> (lg * 8 + 2 * j)) & 3u;
          q[j] = ((b2 | (b2 << 15)) & 0x10001u) * 0x3F80u;
        }
        const bf16x8 af = *reinterpret_cast<const bf16x8*>(&q);
        if (mf == 0) {
#pragma unroll
          for (int nf = 0; nf < 8; ++nf) acc[0][nf] = MFMA16(af, bb[nf * 2 + kf], acc[0][nf]);
        } else {
#pragma unroll
          for (int nf = 0; nf < 8; ++nf) acc[1][nf] = MFMA16(af, bb[nf * 2 + kf], acc[1][nf]);
        }
      }
    }
  }

  // exclusive partial store
  float* po = outp + (size_t)ks * NN * DOUT;
#pragma unroll
  for (int mf = 0; mf < 2; ++mf)
#pragma unroll
    for (int nf = 0; nf < 8; ++nf)
#pragma unroll
      for (int r = 0; r < 4; ++r) {
        const int row = row0 + wm * 32 + mf * 16 + lg * 4 + r;
        const int col = wn * 128 + nf * 16 + lr;
        po[(size_t)row * DOUT + col] = acc[mf][nf][r];
      }
}

// ---------------------------------------------------------------------------
// Kernel 4: out = (sum_ks outp[ks]) / deg
// ---------------------------------------------------------------------------
__global__ __launch_bounds__(256) void k_div(const float* __restrict__ outp,
                                             const int* __restrict__ deg,
                                             float* __restrict__ out) {
  const int idx = blockIdx.x * 256 + threadIdx.x;
  const size_t i4 = (size_t)idx * 4;
  const int row = (int)(i4 >> 8); // DOUT=256
  float4v v  = *reinterpret_cast<const float4v*>(outp + i4);
  float4v v1 = *reinterpret_cast<const float4v*>(outp + (size_t)1 * NN * DOUT + i4);
  float4v v2 = *reinterpret_cast<const float4v*>(outp + (size_t)2 * NN * DOUT + i4);
  float4v v3 = *reinterpret_cast<const float4v*>(outp + (size_t)3 * NN * DOUT + i4);
  const float s = 1.0f / (float)deg[row];
  v[0] = (v[0] + v1[0] + v2[0] + v3[0]) * s;
  v[1] = (v[1] + v1[1] + v2[1] + v3[1]) * s;
  v[2] = (v[2] + v1[2] + v2[2] + v3[2]) * s;
  v[3] = (v[3] + v1[3] + v2[3] + v3[3]) * s;
  *reinterpret_cast<float4v*>(out + i4) = v;
}

// ---------------------------------------------------------------------------
extern "C" void kernel_launch(void* const* d_in, const int* in_sizes, int n_in,
                              void* d_out, int out_size, void* d_ws, size_t ws_size,
                              hipStream_t stream) {
  const float* x   = (const float*)d_in[0]; // [8192][512] f32
  const int*   adj = (const int*)d_in[1];   // [8192][8192] i32 (0/1)
  const float* W   = (const float*)d_in[2]; // [512][256] f32
  float* out = (float*)d_out;               // [8192][256] f32

  char* ws = (char*)d_ws;
  unsigned short* xw_t = (unsigned short*)ws;                               // 4 MB
  unsigned short* Wt   = (unsigned short*)(ws + (size_t)4 * 1024 * 1024);   // 256 KB
  int*            deg  = (int*)(ws + (size_t)4 * 1024 * 1024 + 512 * 1024); // 32 KB
  unsigned int*   bits = (unsigned int*)(ws + (size_t)5 * 1024 * 1024);     // 8 MB
  float*          outp = (float*)(ws + (size_t)16 * 1024 * 1024);           // 32 MB

  k_wt<<<256, 128, 0, stream>>>(W, Wt);
  k_xwt<<<128, 256, 0, stream>>>(x, Wt, xw_t);
  k_pack<<<NN / 4, 256, 0, stream>>>(adj, bits, deg);
  k_agg<<<(NN / BM) * KSPLIT, 256, 0, stream>>>(bits, xw_t, outp);
  k_div<<<(NN * DOUT) / (256 * 4), 256, 0, stream>>>(outp, deg, out);
}

// Round 6
// 170.011 us; speedup vs baseline: 1.3290x; 1.2688x over previous
//
#include <hip/hip_runtime.h>
#include <stdint.h>

typedef __attribute__((ext_vector_type(8))) short  bf16x8;
typedef __attribute__((ext_vector_type(4))) float  f32x4;
typedef __attribute__((ext_vector_type(4))) int    int4v;
typedef __attribute__((ext_vector_type(4))) float  float4v;
typedef __attribute__((ext_vector_type(4))) unsigned int uint4v;
typedef __attribute__((ext_vector_type(2))) unsigned int uint2v;

#define NN   8192   // nodes
#define DIN  512
#define DOUT 256
#define NW   (NN / 32)   // 256 dwords of bits per row

// k_agg geometry
#define BM2     256
#define KSPLIT2 8
#define KS2     (NN / KSPLIT2)  // 1024
#define BK2     64
#define NTK     (KS2 / BK2)     // 16

#define MFMA16(a, b, c) __builtin_amdgcn_mfma_f32_16x16x32_bf16((a), (b), (c), 0, 0, 0)

__device__ __forceinline__ unsigned short f2bf(float f) {
  unsigned u = __float_as_uint(f);
  return (unsigned short)((u + 0x7FFFu + ((u >> 16) & 1u)) >> 16);
}

__device__ __forceinline__ void gld16(const void* g, void* s) {
  __builtin_amdgcn_global_load_lds(
      (const __attribute__((address_space(1))) unsigned int*)g,
      (__attribute__((address_space(3))) unsigned int*)s, 16, 0, 0);
}

// ---------------------------------------------------------------------------
// Kernel 0: Wt[n][c] = bf16(W[c][n]).  W: [512][256] f32 -> Wt: [256][512] bf16
// ---------------------------------------------------------------------------
__global__ void k_wt(const float* __restrict__ W, unsigned short* __restrict__ Wt) {
  int n = blockIdx.x; // 0..255
  for (int c = threadIdx.x; c < DIN; c += blockDim.x)
    Wt[n * DIN + c] = f2bf(W[c * DOUT + n]);
}

// ---------------------------------------------------------------------------
// Kernel 1: xw_t[n][m] = sum_c x[m][c] * W[c][n]   (bf16 out, transposed)
// ---------------------------------------------------------------------------
__global__ __launch_bounds__(256) void k_xwt(const float* __restrict__ x,
                                             const unsigned short* __restrict__ Wt,
                                             unsigned short* __restrict__ xw_t) {
  const int mb = blockIdx.x >> 1, nb = blockIdx.x & 1;
  const int tid = threadIdx.x;
  const int w = tid >> 6, l = tid & 63;
  const int wm = w >> 1, wn = w & 1;
  const int lr = l & 15, lg = l >> 4;
  const int m_base = mb * 128 + wm * 64;
  const int n_base = nb * 128 + wn * 64;

  f32x4 acc[4][4];
  for (int i = 0; i < 4; ++i)
    for (int j = 0; j < 4; ++j) acc[i][j] = (f32x4)0.0f;

  for (int c0 = 0; c0 < DIN; c0 += 32) {
    const int c = c0 + lg * 8;
    bf16x8 af[4], bfv[4];
#pragma unroll
    for (int mt = 0; mt < 4; ++mt) {
      const float* xp = x + (size_t)(m_base + mt * 16 + lr) * DIN + c;
      float4v x0 = *reinterpret_cast<const float4v*>(xp);
      float4v x1 = *reinterpret_cast<const float4v*>(xp + 4);
      bf16x8 a;
#pragma unroll
      for (int j = 0; j < 4; ++j) {
        a[j]     = (short)f2bf(x0[j]);
        a[4 + j] = (short)f2bf(x1[j]);
      }
      af[mt] = a;
    }
#pragma unroll
    for (int nt = 0; nt < 4; ++nt)
      bfv[nt] = *reinterpret_cast<const bf16x8*>(Wt + (size_t)(n_base + nt * 16 + lr) * DIN + c);
#pragma unroll
    for (int mt = 0; mt < 4; ++mt)
#pragma unroll
      for (int nt = 0; nt < 4; ++nt)
        acc[mt][nt] = MFMA16(af[mt], bfv[nt], acc[mt][nt]);
  }

#pragma unroll
  for (int nt = 0; nt < 4; ++nt) {
    const int n = n_base + nt * 16 + lr;
#pragma unroll
    for (int mt = 0; mt < 4; ++mt) {
      const int m = m_base + mt * 16 + lg * 4;
      unsigned short b0 = f2bf(acc[mt][nt][0]), b1 = f2bf(acc[mt][nt][1]);
      unsigned short b2 = f2bf(acc[mt][nt][2]), b3 = f2bf(acc[mt][nt][3]);
      uint2v p;
      p[0] = (unsigned)b0 | ((unsigned)b1 << 16);
      p[1] = (unsigned)b2 | ((unsigned)b3 << 16);
      *reinterpret_cast<uint2v*>(xw_t + (size_t)n * NN + m) = p;
    }
  }
}

// ---------------------------------------------------------------------------
// Kernel 2: pack adj -> bits + deg. Wave-per-row, lane owns 128 ints (512 B).
// No shfl in the hot path, no barriers; per-lane 32 int4 loads in flight.
// ---------------------------------------------------------------------------
__global__ __launch_bounds__(256) void k_pack(const int* __restrict__ adj,
                                              unsigned int* __restrict__ bits,
                                              int* __restrict__ deg) {
  const int tid = threadIdx.x;
  const int w = tid >> 6, l = tid & 63;
  const int row = blockIdx.x * 4 + w;
  const int* src = adj + (size_t)row * NN + l * 128;

  int cnt = 0;
  uint4v outw;
#pragma unroll
  for (int j = 0; j < 4; ++j) {       // one dword per j
    unsigned word = 0;
#pragma unroll
    for (int i = 0; i < 8; ++i) {     // 4 ints per load
      int4v v = *reinterpret_cast<const int4v*>(src + j * 32 + i * 4);
      cnt += v[0] + v[1] + v[2] + v[3];
      word |= ((unsigned)v[0] << (i * 4)) | ((unsigned)v[1] << (i * 4 + 1)) |
              ((unsigned)v[2] << (i * 4 + 2)) | ((unsigned)v[3] << (i * 4 + 3));
    }
    outw[j] = word;
  }
  *reinterpret_cast<uint4v*>(bits + (size_t)row * NW + l * 4) = outw;

  cnt += __shfl_xor(cnt, 1);
  cnt += __shfl_xor(cnt, 2);
  cnt += __shfl_xor(cnt, 4);
  cnt += __shfl_xor(cnt, 8);
  cnt += __shfl_xor(cnt, 16);
  cnt += __shfl_xor(cnt, 32);
  if (l == 0) deg[row] = cnt;
}

// ---------------------------------------------------------------------------
// Kernel 3: split-K partial  outp[ks] = A_bits[rows,kslice] * xw[kslice,:]
// BM=256, BN=256, BK=64, KSPLIT=8. grid 256 (1 block/CU), block 512 = 8 waves
// (2 wm x 4 wn); wave = 128m x 64n. ks = bid&7 -> XCD-pinned: all 32 blocks
// on an XCD re-read the same 512 KB xw_t slice from local L2.
// B: per-K-tile 32 KB staged to LDS dbuf via global_load_lds (16B), source
// pre-swizzled so linear LDS + XOR'd ds_read_b128 is bank-conflict-free.
// A: 1-bit rows, 8 B/row/tile, register-prefetched from global (L2-hot).
// One barrier per tile. Exclusive partial stores, no atomics.
// ---------------------------------------------------------------------------
__global__ __launch_bounds__(512, 2) void k_agg(const unsigned int* __restrict__ bits,
                                                const unsigned short* __restrict__ xw_t,
                                                float* __restrict__ outp) {
  __shared__ unsigned short Bs[2][16384]; // 32 KB per buffer

  const int tid = threadIdx.x;
  const int w = tid >> 6, l = tid & 63;
  const int lr = l & 15, lg = l >> 4;
  const int wm = w >> 2, wn = w & 3;

  const int bid = blockIdx.x;
  const int ks = bid & 7;        // XCD pin
  const int rb = bid >> 3;       // 0..31
  const int row0 = rb * BM2;

  // B staging source: LDS slot S = p*8192 + w*1024 + lane*16 bytes holds
  // row n = S>>7, 16B-block j = (S>>4)&7, pre-swizzled: data block j^(n&7).
  const int sn = tid >> 3;       // = p-relative row (p*64 + sn overall)
  const int sj = tid & 7;
  const unsigned short* gB = xw_t + (size_t)sn * NN + ks * KS2 + ((sj ^ (sn & 7)) * 8);

  // A-bit rows for this lane (mf adds 16 rows)
  const unsigned int* gA = bits + (size_t)(row0 + wm * 128 + lr) * NW + ks * (KS2 >> 5);

  f32x4 acc[8][4];
#pragma unroll
  for (int i = 0; i < 8; ++i)
#pragma unroll
    for (int j = 0; j < 4; ++j) acc[i][j] = (f32x4)0.0f;

  uint2v Ab[8], An[8];

#define STAGE_B(t, buf) do {                                                   \
    _Pragma("unroll")                                                          \
    for (int p_ = 0; p_ < 4; ++p_)                                             \
      gld16(gB + (size_t)p_ * 64 * NN + (t) * BK2,                             \
            (char*)&Bs[buf][0] + p_ * 8192 + w * 1024);                        \
  } while (0)

#define LOADA(t, arr) do {                                                     \
    _Pragma("unroll")                                                          \
    for (int mf_ = 0; mf_ < 8; ++mf_)                                          \
      arr[mf_] = *reinterpret_cast<const uint2v*>(gA + (size_t)mf_ * 16 * NW + 2 * (t)); \
  } while (0)

#define COMPUTE(buf) do {                                                      \
    _Pragma("unroll")                                                          \
    for (int kf_ = 0; kf_ < 2; ++kf_) {                                        \
      bf16x8 bf_[4];                                                           \
      _Pragma("unroll")                                                        \
      for (int nf_ = 0; nf_ < 4; ++nf_) {                                      \
        const int n_ = wn * 64 + nf_ * 16 + lr;                                \
        bf_[nf_] = *reinterpret_cast<const bf16x8*>(                           \
            &Bs[buf][n_ * 64 + (((kf_ * 4 + lg) ^ (n_ & 7)) * 8)]);            \
      }                                                                        \
      _Pragma("unroll")                                                        \
      for (int mf_ = 0; mf_ < 8; ++mf_) {                                      \
        const unsigned a32_ = Ab[mf_][kf_];                                    \
        uint4v q_;                                                             \
        _Pragma("unroll")                                                      \
        for (int j_ = 0; j_ < 4; ++j_) {                                       \
          unsigned b2_ = (a32_ >> (lg * 8 + 2 * j_)) & 3u;                     \
          q_[j_] = ((b2_ | (b2_ << 15)) & 0x10001u) * 0x3F80u;                 \
        }                                                                      \
        const bf16x8 af_ = *reinterpret_cast<const bf16x8*>(&q_);              \
        acc[mf_][0] = MFMA16(af_, bf_[0], acc[mf_][0]);                        \
        acc[mf_][1] = MFMA16(af_, bf_[1], acc[mf_][1]);                        \
        acc[mf_][2] = MFMA16(af_, bf_[2], acc[mf_][2]);                        \
        acc[mf_][3] = MFMA16(af_, bf_[3], acc[mf_][3]);                        \
      }                                                                        \
    }                                                                          \
  } while (0)

  // prologue
  STAGE_B(0, 0);
  LOADA(0, Ab);
  __syncthreads();

  for (int t = 0; t < NTK; ++t) {
    const int buf = t & 1;
    if (t + 1 < NTK) {
      STAGE_B(t + 1, buf ^ 1);
      LOADA(t + 1, An);
    }
    COMPUTE(buf);
#pragma unroll
    for (int mf = 0; mf < 8; ++mf) Ab[mf] = An[mf];
    __syncthreads();
  }
#undef STAGE_B
#undef LOADA
#undef COMPUTE

  // exclusive partial store
  float* po = outp + (size_t)ks * NN * DOUT;
#pragma unroll
  for (int mf = 0; mf < 8; ++mf)
#pragma unroll
    for (int nf = 0; nf < 4; ++nf)
#pragma unroll
      for (int r = 0; r < 4; ++r) {
        const int row = row0 + wm * 128 + mf * 16 + lg * 4 + r;
        const int col = wn * 64 + nf * 16 + lr;
        po[(size_t)row * DOUT + col] = acc[mf][nf][r];
      }
}

// ---------------------------------------------------------------------------
// Kernel 4: out = (sum_ks outp[ks]) / deg
// ---------------------------------------------------------------------------
__global__ __launch_bounds__(256) void k_div(const float* __restrict__ outp,
                                             const int* __restrict__ deg,
                                             float* __restrict__ out) {
  const int idx = blockIdx.x * 256 + threadIdx.x;
  const size_t i4 = (size_t)idx * 4;
  const int row = (int)(i4 >> 8); // DOUT=256
  float4v s = *reinterpret_cast<const float4v*>(outp + i4);
#pragma unroll
  for (int p = 1; p < KSPLIT2; ++p) {
    float4v v = *reinterpret_cast<const float4v*>(outp + (size_t)p * NN * DOUT + i4);
    s[0] += v[0]; s[1] += v[1]; s[2] += v[2]; s[3] += v[3];
  }
  const float sc = 1.0f / (float)deg[row];
  s[0] *= sc; s[1] *= sc; s[2] *= sc; s[3] *= sc;
  *reinterpret_cast<float4v*>(out + i4) = s;
}

// ---------------------------------------------------------------------------
extern "C" void kernel_launch(void* const* d_in, const int* in_sizes, int n_in,
                              void* d_out, int out_size, void* d_ws, size_t ws_size,
                              hipStream_t stream) {
  const float* x   = (const float*)d_in[0]; // [8192][512] f32
  const int*   adj = (const int*)d_in[1];   // [8192][8192] i32 (0/1)
  const float* W   = (const float*)d_in[2]; // [512][256] f32
  float* out = (float*)d_out;               // [8192][256] f32

  char* ws = (char*)d_ws;
  unsigned short* xw_t = (unsigned short*)ws;                               // 4 MB
  unsigned short* Wt   = (unsigned short*)(ws + (size_t)4 * 1024 * 1024);   // 256 KB
  int*            deg  = (int*)(ws + (size_t)4 * 1024 * 1024 + 512 * 1024); // 32 KB
  unsigned int*   bits = (unsigned int*)(ws + (size_t)5 * 1024 * 1024);     // 8 MB
  float*          outp = (float*)(ws + (size_t)16 * 1024 * 1024);           // 64 MB

  k_wt<<<256, 128, 0, stream>>>(W, Wt);
  k_xwt<<<128, 256, 0, stream>>>(x, Wt, xw_t);
  k_pack<<<NN / 4, 256, 0, stream>>>(adj, bits, deg);
  k_agg<<<(NN / BM2) * KSPLIT2, 512, 0, stream>>>(bits, xw_t, outp);
  k_div<<<(NN * DOUT) / (256 * 4), 256, 0, stream>>>(outp, deg, out);
}

// Round 7
// 152.054 us; speedup vs baseline: 1.4860x; 1.1181x over previous
//
#include <hip/hip_runtime.h>
#include <stdint.h>

typedef __attribute__((ext_vector_type(8))) short  bf16x8;
typedef __attribute__((ext_vector_type(4))) float  f32x4;
typedef __attribute__((ext_vector_type(4))) int    int4v;
typedef __attribute__((ext_vector_type(4))) float  float4v;
typedef __attribute__((ext_vector_type(4))) unsigned int uint4v;
typedef __attribute__((ext_vector_type(2))) unsigned int uint2v;

#define NN   8192   // nodes
#define DIN  512
#define DOUT 256
#define NW   (NN / 32)   // 256 dwords of bits per row

// k_agg geometry
#define BM2     256
#define KSPLIT2 8
#define KS2     (NN / KSPLIT2)  // 1024
#define BK2     64
#define NTK     (KS2 / BK2)     // 16

#define MFMA16(a, b, c) __builtin_amdgcn_mfma_f32_16x16x32_bf16((a), (b), (c), 0, 0, 0)

__device__ __forceinline__ unsigned short f2bf(float f) {
  unsigned u = __float_as_uint(f);
  return (unsigned short)((u + 0x7FFFu + ((u >> 16) & 1u)) >> 16);
}

__device__ __forceinline__ void gld16(const void* g, void* s) {
  __builtin_amdgcn_global_load_lds(
      (const __attribute__((address_space(1))) unsigned int*)g,
      (__attribute__((address_space(3))) unsigned int*)s, 16, 0, 0);
}

// ---------------------------------------------------------------------------
// Kernel 0: Wt[n][c] = bf16(W[c][n]).  W: [512][256] f32 -> Wt: [256][512] bf16
// ---------------------------------------------------------------------------
__global__ void k_wt(const float* __restrict__ W, unsigned short* __restrict__ Wt) {
  int n = blockIdx.x; // 0..255
  for (int c = threadIdx.x; c < DIN; c += blockDim.x)
    Wt[n * DIN + c] = f2bf(W[c * DOUT + n]);
}

// ---------------------------------------------------------------------------
// Kernel 1: xw_t[n][m] = sum_c x[m][c] * W[c][n]   (bf16 out, transposed)
// ---------------------------------------------------------------------------
__global__ __launch_bounds__(256) void k_xwt(const float* __restrict__ x,
                                             const unsigned short* __restrict__ Wt,
                                             unsigned short* __restrict__ xw_t) {
  const int mb = blockIdx.x >> 1, nb = blockIdx.x & 1;
  const int tid = threadIdx.x;
  const int w = tid >> 6, l = tid & 63;
  const int wm = w >> 1, wn = w & 1;
  const int lr = l & 15, lg = l >> 4;
  const int m_base = mb * 128 + wm * 64;
  const int n_base = nb * 128 + wn * 64;

  f32x4 acc[4][4];
  for (int i = 0; i < 4; ++i)
    for (int j = 0; j < 4; ++j) acc[i][j] = (f32x4)0.0f;

  for (int c0 = 0; c0 < DIN; c0 += 32) {
    const int c = c0 + lg * 8;
    bf16x8 af[4], bfv[4];
#pragma unroll
    for (int mt = 0; mt < 4; ++mt) {
      const float* xp = x + (size_t)(m_base + mt * 16 + lr) * DIN + c;
      float4v x0 = *reinterpret_cast<const float4v*>(xp);
      float4v x1 = *reinterpret_cast<const float4v*>(xp + 4);
      bf16x8 a;
#pragma unroll
      for (int j = 0; j < 4; ++j) {
        a[j]     = (short)f2bf(x0[j]);
        a[4 + j] = (short)f2bf(x1[j]);
      }
      af[mt] = a;
    }
#pragma unroll
    for (int nt = 0; nt < 4; ++nt)
      bfv[nt] = *reinterpret_cast<const bf16x8*>(Wt + (size_t)(n_base + nt * 16 + lr) * DIN + c);
#pragma unroll
    for (int mt = 0; mt < 4; ++mt)
#pragma unroll
      for (int nt = 0; nt < 4; ++nt)
        acc[mt][nt] = MFMA16(af[mt], bfv[nt], acc[mt][nt]);
  }

#pragma unroll
  for (int nt = 0; nt < 4; ++nt) {
    const int n = n_base + nt * 16 + lr;
#pragma unroll
    for (int mt = 0; mt < 4; ++mt) {
      const int m = m_base + mt * 16 + lg * 4;
      unsigned short b0 = f2bf(acc[mt][nt][0]), b1 = f2bf(acc[mt][nt][1]);
      unsigned short b2 = f2bf(acc[mt][nt][2]), b3 = f2bf(acc[mt][nt][3]);
      uint2v p;
      p[0] = (unsigned)b0 | ((unsigned)b1 << 16);
      p[1] = (unsigned)b2 | ((unsigned)b3 << 16);
      *reinterpret_cast<uint2v*>(xw_t + (size_t)n * NN + m) = p;
    }
  }
}

// ---------------------------------------------------------------------------
// Kernel 2: pack adj -> bits + deg via wave ballot. Block = 1 row, 4 waves;
// wave w covers ints [w*2048, w*2048+2048). Per iteration a wave reads 64
// CONSECUTIVE ints (one coalesced 256 B instruction), __ballot(v!=0) builds
// the 64-bit mask, lane 0 stores 8 B, __popcll accumulates deg. Unroll 8
// keeps 8 loads in flight per wave.
// ---------------------------------------------------------------------------
__global__ __launch_bounds__(256) void k_pack(const int* __restrict__ adj,
                                              unsigned int* __restrict__ bits,
                                              int* __restrict__ deg) {
  __shared__ int wsum[4];
  const int tid = threadIdx.x;
  const int w = tid >> 6, l = tid & 63;
  const int row = blockIdx.x;
  const int* src = adj + (size_t)row * NN + w * 2048 + l;
  unsigned long long* bdst =
      reinterpret_cast<unsigned long long*>(bits + (size_t)row * NW + w * 64);

  int cnt = 0;
#pragma unroll
  for (int it = 0; it < 32; it += 8) {
    unsigned long long b[8];
#pragma unroll
    for (int u = 0; u < 8; ++u)
      b[u] = __ballot(src[(it + u) * 64] != 0);
#pragma unroll
    for (int u = 0; u < 8; ++u) {
      if (l == 0) bdst[it + u] = b[u];
      cnt += (int)__popcll(b[u]);
    }
  }

  if (l == 0) wsum[w] = cnt;
  __syncthreads();
  if (tid == 0) deg[row] = wsum[0] + wsum[1] + wsum[2] + wsum[3];
}

// ---------------------------------------------------------------------------
// Kernel 3: split-K partial  outp[ks] = A_bits[rows,kslice] * xw[kslice,:]
// BM=256, BN=256, BK=64, KSPLIT=8. grid 256 (1 block/CU), block 512 = 8 waves
// (2 wm x 4 wn); wave = 128m x 64n. ks = bid&7 -> XCD-pinned. B staged once
// per K-tile (32 KB) into LDS dbuf via global_load_lds(16B), pre-swizzled
// source + XOR'd ds_read_b128. A-bits register-prefetched. 1 barrier/tile.
// ---------------------------------------------------------------------------
__global__ __launch_bounds__(512, 2) void k_agg(const unsigned int* __restrict__ bits,
                                                const unsigned short* __restrict__ xw_t,
                                                float* __restrict__ outp) {
  __shared__ unsigned short Bs[2][16384]; // 32 KB per buffer

  const int tid = threadIdx.x;
  const int w = tid >> 6, l = tid & 63;
  const int lr = l & 15, lg = l >> 4;
  const int wm = w >> 2, wn = w & 3;

  const int bid = blockIdx.x;
  const int ks = bid & 7;        // XCD pin
  const int rb = bid >> 3;       // 0..31
  const int row0 = rb * BM2;

  const int sn = tid >> 3;
  const int sj = tid & 7;
  const unsigned short* gB = xw_t + (size_t)sn * NN + ks * KS2 + ((sj ^ (sn & 7)) * 8);

  const unsigned int* gA = bits + (size_t)(row0 + wm * 128 + lr) * NW + ks * (KS2 >> 5);

  f32x4 acc[8][4];
#pragma unroll
  for (int i = 0; i < 8; ++i)
#pragma unroll
    for (int j = 0; j < 4; ++j) acc[i][j] = (f32x4)0.0f;

  uint2v Ab[8], An[8];

#define STAGE_B(t, buf) do {                                                   \
    _Pragma("unroll")                                                          \
    for (int p_ = 0; p_ < 4; ++p_)                                             \
      gld16(gB + (size_t)p_ * 64 * NN + (t) * BK2,                             \
            (char*)&Bs[buf][0] + p_ * 8192 + w * 1024);                        \
  } while (0)

#define LOADA(t, arr) do {                                                     \
    _Pragma("unroll")                                                          \
    for (int mf_ = 0; mf_ < 8; ++mf_)                                          \
      arr[mf_] = *reinterpret_cast<const uint2v*>(gA + (size_t)mf_ * 16 * NW + 2 * (t)); \
  } while (0)

#define COMPUTE(buf) do {                                                      \
    _Pragma("unroll")                                                          \
    for (int kf_ = 0; kf_ < 2; ++kf_) {                                        \
      bf16x8 bf_[4];                                                           \
      _Pragma("unroll")                                                        \
      for (int nf_ = 0; nf_ < 4; ++nf_) {                                      \
        const int n_ = wn * 64 + nf_ * 16 + lr;                                \
        bf_[nf_] = *reinterpret_cast<const bf16x8*>(                           \
            &Bs[buf][n_ * 64 + (((kf_ * 4 + lg) ^ (n_ & 7)) * 8)]);            \
      }                                                                        \
      _Pragma("unroll")                                                        \
      for (int mf_ = 0; mf_ < 8; ++mf_) {                                      \
        const unsigned a32_ = Ab[mf_][kf_];                                    \
        uint4v q_;                                                             \
        _Pragma("unroll")                                                      \
        for (int j_ = 0; j_ < 4; ++j_) {                                       \
          unsigned b2_ = (a32_ >> (lg * 8 + 2 * j_)) & 3u;                     \
          q_[j_] = ((b2_ | (b2_ << 15)) & 0x10001u) * 0x3F80u;                 \
        }                                                                      \
        const bf16x8 af_ = *reinterpret_cast<const bf16x8*>(&q_);              \
        acc[mf_][0] = MFMA16(af_, bf_[0], acc[mf_][0]);                        \
        acc[mf_][1] = MFMA16(af_, bf_[1], acc[mf_][1]);                        \
        acc[mf_][2] = MFMA16(af_, bf_[2], acc[mf_][2]);                        \
        acc[mf_][3] = MFMA16(af_, bf_[3], acc[mf_][3]);                        \
      }                                                                        \
    }                                                                          \
  } while (0)

  STAGE_B(0, 0);
  LOADA(0, Ab);
  __syncthreads();

  for (int t = 0; t < NTK; ++t) {
    const int buf = t & 1;
    if (t + 1 < NTK) {
      STAGE_B(t + 1, buf ^ 1);
      LOADA(t + 1, An);
    }
    COMPUTE(buf);
#pragma unroll
    for (int mf = 0; mf < 8; ++mf) Ab[mf] = An[mf];
    __syncthreads();
  }
#undef STAGE_B
#undef LOADA
#undef COMPUTE

  float* po = outp + (size_t)ks * NN * DOUT;
#pragma unroll
  for (int mf = 0; mf < 8; ++mf)
#pragma unroll
    for (int nf = 0; nf < 4; ++nf)
#pragma unroll
      for (int r = 0; r < 4; ++r) {
        const int row = row0 + wm * 128 + mf * 16 + lg * 4 + r;
        const int col = wn * 64 + nf * 16 + lr;
        po[(size_t)row * DOUT + col] = acc[mf][nf][r];
      }
}

// ---------------------------------------------------------------------------
// Kernel 4: out = (sum_ks outp[ks]) / deg
// ---------------------------------------------------------------------------
__global__ __launch_bounds__(256) void k_div(const float* __restrict__ outp,
                                             const int* __restrict__ deg,
                                             float* __restrict__ out) {
  const int idx = blockIdx.x * 256 + threadIdx.x;
  const size_t i4 = (size_t)idx * 4;
  const int row = (int)(i4 >> 8); // DOUT=256
  float4v s = *reinterpret_cast<const float4v*>(outp + i4);
#pragma unroll
  for (int p = 1; p < KSPLIT2; ++p) {
    float4v v = *reinterpret_cast<const float4v*>(outp + (size_t)p * NN * DOUT + i4);
    s[0] += v[0]; s[1] += v[1]; s[2] += v[2]; s[3] += v[3];
  }
  const float sc = 1.0f / (float)deg[row];
  s[0] *= sc; s[1] *= sc; s[2] *= sc; s[3] *= sc;
  *reinterpret_cast<float4v*>(out + i4) = s;
}

// ---------------------------------------------------------------------------
extern "C" void kernel_launch(void* const* d_in, const int* in_sizes, int n_in,
                              void* d_out, int out_size, void* d_ws, size_t ws_size,
                              hipStream_t stream) {
  const float* x   = (const float*)d_in[0]; // [8192][512] f32
  const int*   adj = (const int*)d_in[1];   // [8192][8192] i32 (0/1)
  const float* W   = (const float*)d_in[2]; // [512][256] f32
  float* out = (float*)d_out;               // [8192][256] f32

  char* ws = (char*)d_ws;
  unsigned short* xw_t = (unsigned short*)ws;                               // 4 MB
  unsigned short* Wt   = (unsigned short*)(ws + (size_t)4 * 1024 * 1024);   // 256 KB
  int*            deg  = (int*)(ws + (size_t)4 * 1024 * 1024 + 512 * 1024); // 32 KB
  unsigned int*   bits = (unsigned int*)(ws + (size_t)5 * 1024 * 1024);     // 8 MB
  float*          outp = (float*)(ws + (size_t)16 * 1024 * 1024);           // 64 MB

  k_wt<<<256, 128, 0, stream>>>(W, Wt);
  k_xwt<<<128, 256, 0, stream>>>(x, Wt, xw_t);
  k_pack<<<NN, 256, 0, stream>>>(adj, bits, deg);
  k_agg<<<(NN / BM2) * KSPLIT2, 512, 0, stream>>>(bits, xw_t, outp);
  k_div<<<(NN * DOUT) / (256 * 4), 256, 0, stream>>>(outp, deg, out);
}

// Round 8
// 151.532 us; speedup vs baseline: 1.4911x; 1.0034x over previous
//
#include <hip/hip_runtime.h>
#include <stdint.h>

typedef __attribute__((ext_vector_type(8))) short  bf16x8;
typedef __attribute__((ext_vector_type(4))) float  f32x4;
typedef __attribute__((ext_vector_type(4))) int    int4v;
typedef __attribute__((ext_vector_type(4))) float  float4v;
typedef __attribute__((ext_vector_type(4))) unsigned int uint4v;
typedef __attribute__((ext_vector_type(2))) unsigned int uint2v;

#define NN   8192   // nodes
#define DIN  512
#define DOUT 256
#define NW   (NN / 32)   // 256 dwords of bits per row

// k_agg geometry: BM=128, BN=256, BK=64, KSPLIT=8 -> grid 512 (2 blocks/CU)
#define BM2     128
#define KSPLIT2 8
#define KS2     (NN / KSPLIT2)  // 1024
#define BK2     64
#define NTK     (KS2 / BK2)     // 16

#define MFMA16(a, b, c) __builtin_amdgcn_mfma_f32_16x16x32_bf16((a), (b), (c), 0, 0, 0)

__device__ __forceinline__ unsigned short f2bf(float f) {
  unsigned u = __float_as_uint(f);
  return (unsigned short)((u + 0x7FFFu + ((u >> 16) & 1u)) >> 16);
}

__device__ __forceinline__ void gld16(const void* g, void* s) {
  __builtin_amdgcn_global_load_lds(
      (const __attribute__((address_space(1))) unsigned int*)g,
      (__attribute__((address_space(3))) unsigned int*)s, 16, 0, 0);
}

// ---------------------------------------------------------------------------
// Kernel 0: Wt[n][c] = bf16(W[c][n]).  W: [512][256] f32 -> Wt: [256][512] bf16
// ---------------------------------------------------------------------------
__global__ void k_wt(const float* __restrict__ W, unsigned short* __restrict__ Wt) {
  int n = blockIdx.x; // 0..255
  for (int c = threadIdx.x; c < DIN; c += blockDim.x)
    Wt[n * DIN + c] = f2bf(W[c * DOUT + n]);
}

// ---------------------------------------------------------------------------
// Kernel 1: xw_t[n][m] = sum_c x[m][c] * W[c][n]   (bf16 out, transposed)
// ---------------------------------------------------------------------------
__global__ __launch_bounds__(256) void k_xwt(const float* __restrict__ x,
                                             const unsigned short* __restrict__ Wt,
                                             unsigned short* __restrict__ xw_t) {
  const int mb = blockIdx.x >> 1, nb = blockIdx.x & 1;
  const int tid = threadIdx.x;
  const int w = tid >> 6, l = tid & 63;
  const int wm = w >> 1, wn = w & 1;
  const int lr = l & 15, lg = l >> 4;
  const int m_base = mb * 128 + wm * 64;
  const int n_base = nb * 128 + wn * 64;

  f32x4 acc[4][4];
  for (int i = 0; i < 4; ++i)
    for (int j = 0; j < 4; ++j) acc[i][j] = (f32x4)0.0f;

  for (int c0 = 0; c0 < DIN; c0 += 32) {
    const int c = c0 + lg * 8;
    bf16x8 af[4], bfv[4];
#pragma unroll
    for (int mt = 0; mt < 4; ++mt) {
      const float* xp = x + (size_t)(m_base + mt * 16 + lr) * DIN + c;
      float4v x0 = *reinterpret_cast<const float4v*>(xp);
      float4v x1 = *reinterpret_cast<const float4v*>(xp + 4);
      bf16x8 a;
#pragma unroll
      for (int j = 0; j < 4; ++j) {
        a[j]     = (short)f2bf(x0[j]);
        a[4 + j] = (short)f2bf(x1[j]);
      }
      af[mt] = a;
    }
#pragma unroll
    for (int nt = 0; nt < 4; ++nt)
      bfv[nt] = *reinterpret_cast<const bf16x8*>(Wt + (size_t)(n_base + nt * 16 + lr) * DIN + c);
#pragma unroll
    for (int mt = 0; mt < 4; ++mt)
#pragma unroll
      for (int nt = 0; nt < 4; ++nt)
        acc[mt][nt] = MFMA16(af[mt], bfv[nt], acc[mt][nt]);
  }

#pragma unroll
  for (int nt = 0; nt < 4; ++nt) {
    const int n = n_base + nt * 16 + lr;
#pragma unroll
    for (int mt = 0; mt < 4; ++mt) {
      const int m = m_base + mt * 16 + lg * 4;
      unsigned short b0 = f2bf(acc[mt][nt][0]), b1 = f2bf(acc[mt][nt][1]);
      unsigned short b2 = f2bf(acc[mt][nt][2]), b3 = f2bf(acc[mt][nt][3]);
      uint2v p;
      p[0] = (unsigned)b0 | ((unsigned)b1 << 16);
      p[1] = (unsigned)b2 | ((unsigned)b3 << 16);
      *reinterpret_cast<uint2v*>(xw_t + (size_t)n * NN + m) = p;
    }
  }
}

// ---------------------------------------------------------------------------
// Kernel 2: pack adj -> bits + deg via wave ballot (unchanged from r7).
// ---------------------------------------------------------------------------
__global__ __launch_bounds__(256) void k_pack(const int* __restrict__ adj,
                                              unsigned int* __restrict__ bits,
                                              int* __restrict__ deg) {
  __shared__ int wsum[4];
  const int tid = threadIdx.x;
  const int w = tid >> 6, l = tid & 63;
  const int row = blockIdx.x;
  const int* src = adj + (size_t)row * NN + w * 2048 + l;
  unsigned long long* bdst =
      reinterpret_cast<unsigned long long*>(bits + (size_t)row * NW + w * 64);

  int cnt = 0;
#pragma unroll
  for (int it = 0; it < 32; it += 8) {
    unsigned long long b[8];
#pragma unroll
    for (int u = 0; u < 8; ++u)
      b[u] = __ballot(src[(it + u) * 64] != 0);
#pragma unroll
    for (int u = 0; u < 8; ++u) {
      if (l == 0) bdst[it + u] = b[u];
      cnt += (int)__popcll(b[u]);
    }
  }

  if (l == 0) wsum[w] = cnt;
  __syncthreads();
  if (tid == 0) deg[row] = wsum[0] + wsum[1] + wsum[2] + wsum[3];
}

// ---------------------------------------------------------------------------
// Kernel 3: split-K partial  outp[ks] = A_bits[rows,kslice] * xw[kslice,:]
// BM=128, BN=256, BK=64, KSPLIT=8. grid 512 (2 blocks/CU), block 512 = 8
// waves (2 wm x 4 wn); wave = 64m x 64n -> acc[4][4] = 64 VGPR, total ~126
// -> launch_bounds(512,4) -> 4 waves/SIMD, BOTH blocks resident: cross-block
// overlap hides stage latency + barrier drain (the r7 lockstep tax).
// B staged per K-tile (32 KB) into LDS dbuf via global_load_lds(16B),
// pre-swizzled source + XOR'd ds_read_b128. A-bits register-prefetched.
// ---------------------------------------------------------------------------
__global__ __launch_bounds__(512, 4) void k_agg(const unsigned int* __restrict__ bits,
                                                const unsigned short* __restrict__ xw_t,
                                                float* __restrict__ outp) {
  __shared__ unsigned short Bs[2][16384]; // 32 KB per buffer

  const int tid = threadIdx.x;
  const int w = tid >> 6, l = tid & 63;
  const int lr = l & 15, lg = l >> 4;
  const int wm = w >> 2, wn = w & 3;

  const int bid = blockIdx.x;
  const int ks = bid & 7;        // XCD pin
  const int rb = bid >> 3;       // 0..63
  const int row0 = rb * BM2;

  const int sn = tid >> 3;
  const int sj = tid & 7;
  const unsigned short* gB = xw_t + (size_t)sn * NN + ks * KS2 + ((sj ^ (sn & 7)) * 8);

  const unsigned int* gA = bits + (size_t)(row0 + wm * 64 + lr) * NW + ks * (KS2 >> 5);

  f32x4 acc[4][4];
#pragma unroll
  for (int i = 0; i < 4; ++i)
#pragma unroll
    for (int j = 0; j < 4; ++j) acc[i][j] = (f32x4)0.0f;

  uint2v Ab[4], An[4];

#define STAGE_B(t, buf) do {                                                   \
    _Pragma("unroll")                                                          \
    for (int p_ = 0; p_ < 4; ++p_)                                             \
      gld16(gB + (size_t)p_ * 64 * NN + (t) * BK2,                             \
            (char*)&Bs[buf][0] + p_ * 8192 + w * 1024);                        \
  } while (0)

#define LOADA(t, arr) do {                                                     \
    _Pragma("unroll")                                                          \
    for (int mf_ = 0; mf_ < 4; ++mf_)                                          \
      arr[mf_] = *reinterpret_cast<const uint2v*>(gA + (size_t)mf_ * 16 * NW + 2 * (t)); \
  } while (0)

#define COMPUTE(buf) do {                                                      \
    _Pragma("unroll")                                                          \
    for (int kf_ = 0; kf_ < 2; ++kf_) {                                        \
      bf16x8 bf_[4];                                                           \
      _Pragma("unroll")                                                        \
      for (int nf_ = 0; nf_ < 4; ++nf_) {                                      \
        const int n_ = wn * 64 + nf_ * 16 + lr;                                \
        bf_[nf_] = *reinterpret_cast<const bf16x8*>(                           \
            &Bs[buf][n_ * 64 + (((kf_ * 4 + lg) ^ (n_ & 7)) * 8)]);            \
      }                                                                        \
      _Pragma("unroll")                                                        \
      for (int mf_ = 0; mf_ < 4; ++mf_) {                                      \
        const unsigned a32_ = Ab[mf_][kf_];                                    \
        uint4v q_;                                                             \
        _Pragma("unroll")                                                      \
        for (int j_ = 0; j_ < 4; ++j_) {                                       \
          unsigned b2_ = (a32_ >> (lg * 8 + 2 * j_)) & 3u;                     \
          q_[j_] = ((b2_ | (b2_ << 15)) & 0x10001u) * 0x3F80u;                 \
        }                                                                      \
        const bf16x8 af_ = *reinterpret_cast<const bf16x8*>(&q_);              \
        acc[mf_][0] = MFMA16(af_, bf_[0], acc[mf_][0]);                        \
        acc[mf_][1] = MFMA16(af_, bf_[1], acc[mf_][1]);                        \
        acc[mf_][2] = MFMA16(af_, bf_[2], acc[mf_][2]);                        \
        acc[mf_][3] = MFMA16(af_, bf_[3], acc[mf_][3]);                        \
      }                                                                        \
    }                                                                          \
  } while (0)

  STAGE_B(0, 0);
  LOADA(0, Ab);
  __syncthreads();

  for (int t = 0; t < NTK; ++t) {
    const int buf = t & 1;
    if (t + 1 < NTK) {
      STAGE_B(t + 1, buf ^ 1);
      LOADA(t + 1, An);
    }
    COMPUTE(buf);
#pragma unroll
    for (int mf = 0; mf < 4; ++mf) Ab[mf] = An[mf];
    __syncthreads();
  }
#undef STAGE_B
#undef LOADA
#undef COMPUTE

  float* po = outp + (size_t)ks * NN * DOUT;
#pragma unroll
  for (int mf = 0; mf < 4; ++mf)
#pragma unroll
    for (int nf = 0; nf < 4; ++nf)
#pragma unroll
      for (int r = 0; r < 4; ++r) {
        const int row = row0 + wm * 64 + mf * 16 + lg * 4 + r;
        const int col = wn * 64 + nf * 16 + lr;
        po[(size_t)row * DOUT + col] = acc[mf][nf][r];
      }
}

// ---------------------------------------------------------------------------
// Kernel 4: out = (sum_ks outp[ks]) / deg
// ---------------------------------------------------------------------------
__global__ __launch_bounds__(256) void k_div(const float* __restrict__ outp,
                                             const int* __restrict__ deg,
                                             float* __restrict__ out) {
  const int idx = blockIdx.x * 256 + threadIdx.x;
  const size_t i4 = (size_t)idx * 4;
  const int row = (int)(i4 >> 8); // DOUT=256
  float4v s = *reinterpret_cast<const float4v*>(outp + i4);
#pragma unroll
  for (int p = 1; p < KSPLIT2; ++p) {
    float4v v = *reinterpret_cast<const float4v*>(outp + (size_t)p * NN * DOUT + i4);
    s[0] += v[0]; s[1] += v[1]; s[2] += v[2]; s[3] += v[3];
  }
  const float sc = 1.0f / (float)deg[row];
  s[0] *= sc; s[1] *= sc; s[2] *= sc; s[3] *= sc;
  *reinterpret_cast<float4v*>(out + i4) = s;
}

// ---------------------------------------------------------------------------
extern "C" void kernel_launch(void* const* d_in, const int* in_sizes, int n_in,
                              void* d_out, int out_size, void* d_ws, size_t ws_size,
                              hipStream_t stream) {
  const float* x   = (const float*)d_in[0]; // [8192][512] f32
  const int*   adj = (const int*)d_in[1];   // [8192][8192] i32 (0/1)
  const float* W   = (const float*)d_in[2]; // [512][256] f32
  float* out = (float*)d_out;               // [8192][256] f32

  char* ws = (char*)d_ws;
  unsigned short* xw_t = (unsigned short*)ws;                               // 4 MB
  unsigned short* Wt   = (unsigned short*)(ws + (size_t)4 * 1024 * 1024);   // 256 KB
  int*            deg  = (int*)(ws + (size_t)4 * 1024 * 1024 + 512 * 1024); // 32 KB
  unsigned int*   bits = (unsigned int*)(ws + (size_t)5 * 1024 * 1024);     // 8 MB
  float*          outp = (float*)(ws + (size_t)16 * 1024 * 1024);           // 64 MB

  k_wt<<<256, 128, 0, stream>>>(W, Wt);
  k_xwt<<<128, 256, 0, stream>>>(x, Wt, xw_t);
  k_pack<<<NN, 256, 0, stream>>>(adj, bits, deg);
  k_agg<<<(NN / BM2) * KSPLIT2, 512, 0, stream>>>(bits, xw_t, outp);
  k_div<<<(NN * DOUT) / (256 * 4), 256, 0, stream>>>(outp, deg, out);
}